// Round 24
// baseline (389.709 us; speedup 1.0000x reference)
//
#include <hip/hip_runtime.h>

#define NB 8
#define CH 8
#define N1S 255
#define CROP 257
#define NOUT 255
#define CC (CROP * CROP)   // 66049

static constexpr float PI2 = 6.28318530717958647692f;

__device__ inline unsigned short f2bf(float f) {
  unsigned int u = __float_as_uint(f);
  unsigned int lsb = (u >> 16) & 1u;
  u += 0x7fffu + lsb;
  return (unsigned short)(u >> 16);
}

__global__ void k_fill(unsigned short* __restrict__ out, int n, float v) {
  int i = blockIdx.x * 256 + threadIdx.x;
  if (i < n) out[i] = f2bf(v);
}

// ---------------- trig tables ----------------
__global__ void k_tables(float* __restrict__ T, float* __restrict__ Tt,
                         float2* __restrict__ D, float2* __restrict__ Dt) {
  int idx = blockIdx.x * blockDim.x + threadIdx.x;
  if (idx < CROP * N1S) {
    int a = idx / N1S, p = idx % N1S;
    int v = (p + 1) * (a - 128);
    int t = v % 512; if (t < 0) t += 512; if (t >= 256) t -= 512;
    float s = sinf((float)t * (PI2 / 512.0f));
    T[a * N1S + p] = s;
    Tt[p * CROP + a] = s;
  }
  if (idx < NOUT * CROP) {
    int k = idx / CROP, j = idx % CROP;
    int v = k * (j - 127);
    int t = v % 513; if (t < 0) t += 513; if (t > 256) t -= 513;
    float ang = (float)t * (PI2 / 513.0f);
    float2 d = make_float2(cosf(ang), -sinf(ang));
    D[k * CROP + j] = d;
    Dt[j * NOUT + k] = d;
  }
}

// ---------------- weight prep: TRIPLET pack (wr, wi_eff, wr+wi_eff) in consumption order ----------------
__global__ void k_wprep(const float* __restrict__ w1re, const float* __restrict__ w1im,
                        const float* __restrict__ w2re, const float* __restrict__ w2im,
                        const float* __restrict__ w3re, const float* __restrict__ w3im,
                        float* __restrict__ wp) {
  int p = blockIdx.x * 256 + threadIdx.x;
  if (p >= 19584) return;
  int l, off;
  if      (p < 576)   { l = 0; off = 0; }
  else if (p < 5184)  { l = 1; off = 576; }
  else if (p < 9792)  { l = 2; off = 5184; }
  else if (p < 14400) { l = 3; off = 9792; }
  else if (p < 19008) { l = 4; off = 14400; }
  else                { l = 5; off = 19008; }
  int q = p - off;
  int cin  = (l == 0) ? 1 : 8;
  int cout = (l == 5) ? 1 : 8;
  int per_b = cin * cout * 9;
  int b = q / per_b, rem = q % per_b;
  int c = rem / (cout * 9), rem2 = rem % (cout * 9);
  int o = rem2 / 9, t9 = rem2 % 9;
  int di = t9 / 3, dj = t9 % 3;
  const float *wre, *wim;
  if (l == 0 || l == 5) { wre = w1re; wim = w1im; }
  else if (l == 1 || l == 4) { wre = w2re; wim = w2im; }
  else { wre = w3re; wim = w3im; }
  bool trans = (l >= 3);
  float wr, wi;
  if (trans) {
    int widx = (((b * cin + c) * cout + o) * 3 + dj) * 3 + di;
    wr = wre[widx]; wi = -wim[widx];
  } else {
    int widx = (((b * cout + o) * cin + c) * 3 + di) * 3 + dj;
    wr = wre[widx]; wi = wim[widx];
  }
  wp[3 * p] = wr;
  wp[3 * p + 1] = wi;
  wp[3 * p + 2] = wr + wi;
}

// ======== LDS-tiled GEMM kernels: 32x64 tile, 512 thr, 4 out/thr (validated r13) ========

__global__ __launch_bounds__(512) void k_dst1(const float* __restrict__ r,
                                              const float* __restrict__ T,
                                              float* __restrict__ tmp) {
  __shared__ float As[32][16];
  __shared__ float Bs[16][64];
  const int tx = threadIdx.x, ty = threadIdx.y;
  const int tid = ty * 64 + tx;
  const int b = blockIdx.z;
  const int n = blockIdx.x * 64 + tx;
  const int a_base = blockIdx.y * 32;
  const float* rb = r + (size_t)b * N1S * N1S;
  float acc[4] = {};
  for (int mc = 0; mc < N1S; mc += 16) {
    { int row = tid / 16, col = tid % 16;
      int a = a_base + row, m = mc + col;
      As[row][col] = (a < CROP && m < N1S) ? T[a * N1S + m] : 0.f; }
    { int row = tid / 64, col = tid % 64;
      #pragma unroll
      for (int rr = 0; rr < 2; ++rr) {
        int m = mc + row + rr * 8, nn = blockIdx.x * 64 + col;
        Bs[row + rr * 8][col] = (m < N1S && nn < N1S) ? rb[m * N1S + nn] : 0.f;
      } }
    __syncthreads();
    #pragma unroll
    for (int jj = 0; jj < 16; ++jj) {
      float x = Bs[jj][tx];
      #pragma unroll
      for (int q = 0; q < 4; ++q)
        acc[q] = fmaf(As[ty * 4 + q][jj], x, acc[q]);
    }
    __syncthreads();
  }
  if (n < N1S) {
    #pragma unroll
    for (int q = 0; q < 4; ++q) {
      int a = a_base + ty * 4 + q;
      if (a < CROP) tmp[((size_t)b * CROP + a) * N1S + n] = acc[q];
    }
  }
}

__global__ __launch_bounds__(512) void k_dst2(const float* __restrict__ tmp,
                                              const float* __restrict__ Tt,
                                              float2* __restrict__ z0) {
  __shared__ float As[32][16];
  __shared__ float Bs[16][64];
  const int tx = threadIdx.x, ty = threadIdx.y;
  const int tid = ty * 64 + tx;
  const int b = blockIdx.z;
  const int a2 = blockIdx.x * 64 + tx;
  const int a_base = blockIdx.y * 32;
  const float* tb = tmp + (size_t)b * CROP * N1S;
  float acc[4] = {};
  for (int nc = 0; nc < N1S; nc += 16) {
    { int row = tid / 16, col = tid % 16;
      int a1 = a_base + row, nn = nc + col;
      As[row][col] = (a1 < CROP && nn < N1S) ? tb[a1 * N1S + nn] : 0.f; }
    { int row = tid / 64, col = tid % 64;
      #pragma unroll
      for (int rr = 0; rr < 2; ++rr) {
        int nn = nc + row + rr * 8, aa2 = blockIdx.x * 64 + col;
        Bs[row + rr * 8][col] = (nn < N1S && aa2 < CROP) ? Tt[nn * CROP + aa2] : 0.f;
      } }
    __syncthreads();
    #pragma unroll
    for (int jj = 0; jj < 16; ++jj) {
      float x = Bs[jj][tx];
      #pragma unroll
      for (int q = 0; q < 4; ++q)
        acc[q] = fmaf(As[ty * 4 + q][jj], x, acc[q]);
    }
    __syncthreads();
  }
  if (a2 < CROP) {
    #pragma unroll
    for (int q = 0; q < 4; ++q) {
      int a1 = a_base + ty * 4 + q;
      if (a1 < CROP)
        z0[((size_t)b * CROP + a1) * CROP + a2] = make_float2(acc[q] * (-1.0f / 65536.0f), 0.f);
    }
  }
}

__global__ __launch_bounds__(512) void k_f1(const float2* __restrict__ z,
                                            const float2* __restrict__ D,
                                            float2* __restrict__ t) {
  __shared__ float2 As[32][16];
  __shared__ float2 Bs[16][64];
  const int tx = threadIdx.x, ty = threadIdx.y;
  const int tid = ty * 64 + tx;
  const int b = blockIdx.z;
  const int j2 = blockIdx.x * 64 + tx;
  const int k_base = blockIdx.y * 32;
  const float2* zb = z + (size_t)b * CC;
  float tr[4] = {}, ti[4] = {};
  for (int jc = 0; jc < CROP; jc += 16) {
    { int row = tid / 16, col = tid % 16;
      int k = k_base + row, j1 = jc + col;
      As[row][col] = (k < NOUT && j1 < CROP) ? D[k * CROP + j1] : make_float2(0.f, 0.f); }
    { int row = tid / 64, col = tid % 64;
      #pragma unroll
      for (int rr = 0; rr < 2; ++rr) {
        int j1 = jc + row + rr * 8, jj2 = blockIdx.x * 64 + col;
        Bs[row + rr * 8][col] = (j1 < CROP && jj2 < CROP) ? zb[j1 * CROP + jj2] : make_float2(0.f, 0.f);
      } }
    __syncthreads();
    #pragma unroll
    for (int jj = 0; jj < 16; ++jj) {
      float2 zv = Bs[jj][tx];
      #pragma unroll
      for (int q = 0; q < 4; ++q) {
        float2 d = As[ty * 4 + q][jj];
        tr[q] = fmaf(d.x, zv.x, tr[q]); tr[q] = fmaf(-d.y, zv.y, tr[q]);
        ti[q] = fmaf(d.x, zv.y, ti[q]); ti[q] = fmaf(d.y, zv.x, ti[q]);
      }
    }
    __syncthreads();
  }
  if (j2 < CROP) {
    #pragma unroll
    for (int q = 0; q < 4; ++q) {
      int k = k_base + ty * 4 + q;
      if (k < NOUT)
        t[((size_t)b * NOUT + k) * CROP + j2] = make_float2(tr[q], ti[q]);
    }
  }
}

__global__ __launch_bounds__(512) void k_f2(const float2* __restrict__ t,
                                            const float2* __restrict__ Dt,
                                            ushort2* __restrict__ out) {
  __shared__ float2 As[32][16];
  __shared__ float2 Bs[16][64];
  const int tx = threadIdx.x, ty = threadIdx.y;
  const int tid = ty * 64 + tx;
  const int b = blockIdx.z;
  const int k2 = blockIdx.x * 64 + tx;
  const int k_base = blockIdx.y * 32;
  const float2* tb = t + (size_t)b * NOUT * CROP;
  float er[4] = {}, ei[4] = {};
  for (int jc = 0; jc < CROP; jc += 16) {
    { int row = tid / 16, col = tid % 16;
      int k1 = k_base + row, j = jc + col;
      As[row][col] = (k1 < NOUT && j < CROP) ? tb[k1 * CROP + j] : make_float2(0.f, 0.f); }
    { int row = tid / 64, col = tid % 64;
      #pragma unroll
      for (int rr = 0; rr < 2; ++rr) {
        int j = jc + row + rr * 8, kk2 = blockIdx.x * 64 + col;
        Bs[row + rr * 8][col] = (j < CROP && kk2 < NOUT) ? Dt[j * NOUT + kk2] : make_float2(0.f, 0.f);
      } }
    __syncthreads();
    #pragma unroll
    for (int jj = 0; jj < 16; ++jj) {
      float2 dv = Bs[jj][tx];
      #pragma unroll
      for (int q = 0; q < 4; ++q) {
        float2 tv = As[ty * 4 + q][jj];
        er[q] = fmaf(tv.x, dv.x, er[q]); er[q] = fmaf(-tv.y, dv.y, er[q]);
        ei[q] = fmaf(tv.x, dv.y, ei[q]); ei[q] = fmaf(tv.y, dv.x, ei[q]);
      }
    }
    __syncthreads();
  }
  if (k2 < NOUT) {
    #pragma unroll
    for (int q = 0; q < 4; ++q) {
      int k1 = k_base + ty * 4 + q;
      if (k1 < NOUT)
        out[((size_t)b * NOUT + k1) * NOUT + k2] = make_ushort2(f2bf(ei[q]), f2bf(er[q]));
    }
  }
}

// ---------------- FUSED 2-layer conv, LDS aliasing + single-group Karatsuba ----------------
// __launch_bounds__(256, 4): min 4 waves/EU -> allows up to ~128 VGPR so the
// 24 accumulators + 27-float window stay in registers (r22/r23 were capped at 36 VGPR).
template<int CIN, int COUT2, bool THETA_MID, bool REALIN>
__global__ __launch_bounds__(256, 4) void k_fused(const float2* __restrict__ in,
                                                  const float* __restrict__ wlA,
                                                  const float* __restrict__ wlB,
                                                  const float* __restrict__ tre,
                                                  const float* __restrict__ tim,
                                                  float2* __restrict__ out) {
  constexpr int TSZ = CIN * 18 * 18;
  constexpr int MSZ = 8 * 16 * 17;
  constexpr int SSZ = (TSZ > MSZ) ? TSZ : MSZ;
  __shared__ float2 sh[SSZ];
  const int b = blockIdx.z;
  const int tx = threadIdx.x, ty = threadIdx.y;
  const int tid = ty * 16 + tx;
  const int ox0 = blockIdx.x * 14, oy0 = blockIdx.y * 14;

  // stage input halo
  const float2* inb = in + (size_t)b * CIN * CC;
  #pragma unroll 1
  for (int idx = tid; idx < TSZ; idx += 256) {
    int c = idx / (18 * 18), rem = idx % (18 * 18);
    int iy = rem / 18, ix = rem % 18;
    int gy = oy0 + iy - 2, gx = ox0 + ix - 2;
    float2 v = make_float2(0.f, 0.f);
    if (gy >= 0 && gy < CROP && gx >= 0 && gx < CROP)
      v = inb[(c * CROP + gy) * CROP + gx];
    sh[idx] = v;
  }
  __syncthreads();

  // layer1 -> registers (8 mid channels per thread)
  float mr[8], mi[8];
  {
    const int gmy = oy0 - 1 + ty, gmx = ox0 - 1 + tx;
    const bool inside = (gmy >= 0 && gmy < CROP && gmx >= 0 && gmx < CROP);
    if (REALIN) {
      float ar[8] = {}, ai[8] = {};
      #pragma unroll 1
      for (int c = 0; c < CIN; ++c) {
        const float* wsc = wlA + (size_t)3 * ((b * CIN + c) * 8 * 9);
        float xr[9];
        #pragma unroll
        for (int t9 = 0; t9 < 9; ++t9)
          xr[t9] = sh[(c * 18 + ty + t9 / 3) * 18 + tx + t9 % 3].x;
        #pragma unroll
        for (int o = 0; o < 8; ++o) {
          #pragma unroll
          for (int t9 = 0; t9 < 9; ++t9) {
            float w0 = wsc[(o * 9 + t9) * 3];
            float w1 = wsc[(o * 9 + t9) * 3 + 1];
            ar[o] = fmaf(w0, xr[t9], ar[o]);
            ai[o] = fmaf(w1, xr[t9], ai[o]);
          }
        }
      }
      #pragma unroll
      for (int o = 0; o < 8; ++o) { mr[o] = ar[o]; mi[o] = ai[o]; }
    } else {
      float P1[8] = {}, P2[8] = {}, P3[8] = {};
      #pragma unroll 1
      for (int c = 0; c < CIN; ++c) {
        const float* wsc = wlA + (size_t)3 * ((b * CIN + c) * 8 * 9);
        float xr[9], xi[9], xs[9];
        #pragma unroll
        for (int t9 = 0; t9 < 9; ++t9) {
          float2 v = sh[(c * 18 + ty + t9 / 3) * 18 + tx + t9 % 3];
          xr[t9] = v.x; xi[t9] = v.y; xs[t9] = v.x + v.y;
        }
        #pragma unroll
        for (int o = 0; o < 8; ++o) {
          #pragma unroll
          for (int t9 = 0; t9 < 9; ++t9) {
            float w0 = wsc[(o * 9 + t9) * 3];
            float w1 = wsc[(o * 9 + t9) * 3 + 1];
            float w2 = wsc[(o * 9 + t9) * 3 + 2];
            P1[o] = fmaf(w0, xr[t9], P1[o]);
            P2[o] = fmaf(w1, xi[t9], P2[o]);
            P3[o] = fmaf(w2, xs[t9], P3[o]);
          }
        }
      }
      #pragma unroll
      for (int o = 0; o < 8; ++o) {
        mr[o] = P1[o] - P2[o];
        mi[o] = P3[o] - P1[o] - P2[o];
      }
    }
    #pragma unroll
    for (int o = 0; o < 8; ++o) {
      float rv = mr[o], iv = mi[o];
      if (THETA_MID && inside) {
        size_t tix = ((size_t)(b * 8 + o) * CROP + gmy) * CROP + gmx;
        float trv = tre[tix], tiv = tim[tix];
        float nr = rv * trv - iv * tiv, ni = rv * tiv + iv * trv;
        rv = nr; iv = ni;
      }
      mr[o] = inside ? rv : 0.f;
      mi[o] = inside ? iv : 0.f;
    }
  }
  __syncthreads();   // all tile reads done -> safe to overwrite

  // write mid into the SAME LDS region
  #pragma unroll
  for (int o = 0; o < 8; ++o)
    sh[(o * 16 + ty) * 17 + tx] = make_float2(mr[o], mi[o]);
  __syncthreads();

  // layer2: single-group Karatsuba over all COUT2 outputs
  if (tx < 14 && ty < 14) {
    const int oy = oy0 + ty, ox = ox0 + tx;
    if (oy < CROP && ox < CROP) {
      float P1[COUT2] = {}, P2[COUT2] = {}, P3[COUT2] = {};
      #pragma unroll 1
      for (int c = 0; c < 8; ++c) {
        const float* wsc = wlB + (size_t)3 * ((b * 8 + c) * COUT2 * 9);
        float xr[9], xi[9], xs[9];
        #pragma unroll
        for (int t9 = 0; t9 < 9; ++t9) {
          float2 v = sh[(c * 16 + ty + t9 / 3) * 17 + tx + t9 % 3];
          xr[t9] = v.x; xi[t9] = v.y; xs[t9] = v.x + v.y;
        }
        #pragma unroll
        for (int o = 0; o < COUT2; ++o) {
          #pragma unroll
          for (int t9 = 0; t9 < 9; ++t9) {
            float w0 = wsc[(o * 9 + t9) * 3];
            float w1 = wsc[(o * 9 + t9) * 3 + 1];
            float w2 = wsc[(o * 9 + t9) * 3 + 2];
            P1[o] = fmaf(w0, xr[t9], P1[o]);
            P2[o] = fmaf(w1, xi[t9], P2[o]);
            P3[o] = fmaf(w2, xs[t9], P3[o]);
          }
        }
      }
      float2* outb = out + (size_t)b * COUT2 * CC;
      #pragma unroll
      for (int o = 0; o < COUT2; ++o) {
        float re = P1[o] - P2[o];
        float im = P3[o] - P1[o] - P2[o];
        outb[(o * CROP + oy) * CROP + ox] = make_float2(re, im);
      }
    }
  }
}

extern "C" void kernel_launch(void* const* d_in, const int* in_sizes, int n_in,
                              void* d_out, int out_size, void* d_ws, size_t ws_size,
                              hipStream_t stream) {
  (void)ws_size;
  static const int EXP[9] = {520200, 576, 576, 4608, 4608, 4608, 4608, 4227136, 4227136};
  int bad = -1;
  if (n_in != 9) bad = 90;
  else for (int i = 0; i < 9; ++i) if (in_sizes[i] != EXP[i]) { bad = i; break; }
  if (bad >= 0) {
    float v = (bad == 90) ? 99.0f : (100.0f + (float)bad);
    k_fill<<<(out_size + 255) / 256, 256, 0, stream>>>((unsigned short*)d_out, out_size, v);
    return;
  }

  const float* r    = (const float*)d_in[0];
  const float* w1re = (const float*)d_in[1];
  const float* w1im = (const float*)d_in[2];
  const float* w2re = (const float*)d_in[3];
  const float* w2im = (const float*)d_in[4];
  const float* w3re = (const float*)d_in[5];
  const float* w3im = (const float*)d_in[6];
  const float* thre = (const float*)d_in[7];
  const float* thim = (const float*)d_in[8];

  float* ws = (float*)d_ws;
  size_t off = 0;
  auto alloc = [&](size_t n) { float* p = ws + off; off += (n + 63) & ~(size_t)63; return p; };
  float*  T    = alloc((size_t)CROP * N1S);
  float*  Tt   = alloc((size_t)N1S * CROP);
  float2* D    = (float2*)alloc((size_t)NOUT * CROP * 2);
  float2* Dt   = (float2*)alloc((size_t)CROP * NOUT * 2);
  float*  wp   = alloc((size_t)3 * 19584);
  float*  tmpA = alloc((size_t)NB * CROP * N1S);
  float2* z0   = (float2*)alloc((size_t)NB * CC * 2);
  float2* tmpF = (float2*)alloc((size_t)NB * NOUT * CROP * 2);
  float2* A    = (float2*)alloc((size_t)NB * CH * CC * 2);
  float2* Bb   = (float2*)alloc((size_t)NB * CH * CC * 2);

  k_tables<<<dim3((CROP * N1S + 255) / 256), dim3(256), 0, stream>>>(T, Tt, D, Dt);
  k_wprep<<<dim3(77), dim3(256), 0, stream>>>(w1re, w1im, w2re, w2im, w3re, w3im, wp);
  k_dst1<<<dim3(4, 9, NB), dim3(64, 8), 0, stream>>>(r, T, tmpA);
  k_dst2<<<dim3(5, 9, NB), dim3(64, 8), 0, stream>>>(tmpA, Tt, z0);

  dim3 fgrid(19, 19, NB), fblk(16, 16);
  // {conv1+conv2}, {conv3*theta+convT3}, {convT2+convT1}   (triplet float offsets = 3 * pair-index)
  k_fused<1, 8, false, true ><<<fgrid, fblk, 0, stream>>>(z0, wp + 3 * 0,     wp + 3 * 576,   nullptr, nullptr, A);
  k_fused<8, 8, true , false><<<fgrid, fblk, 0, stream>>>(A,  wp + 3 * 5184,  wp + 3 * 9792,  thre, thim, Bb);
  k_fused<8, 1, false, false><<<fgrid, fblk, 0, stream>>>(Bb, wp + 3 * 14400, wp + 3 * 19008, nullptr, nullptr, z0);

  k_f1<<<dim3(5, 8, NB), dim3(64, 8), 0, stream>>>(z0, D, tmpF);
  k_f2<<<dim3(4, 8, NB), dim3(64, 8), 0, stream>>>(tmpF, Dt, (ushort2*)d_out);
}

// Round 25
// 303.143 us; speedup vs baseline: 1.2856x; 1.2856x over previous
//
#include <hip/hip_runtime.h>

#define NB 8
#define CH 8
#define N1S 255
#define CROP 257
#define NOUT 255
#define CC (CROP * CROP)   // 66049

static constexpr float PI2 = 6.28318530717958647692f;

__device__ inline unsigned short f2bf(float f) {
  unsigned int u = __float_as_uint(f);
  unsigned int lsb = (u >> 16) & 1u;
  u += 0x7fffu + lsb;
  return (unsigned short)(u >> 16);
}

__global__ void k_fill(unsigned short* __restrict__ out, int n, float v) {
  int i = blockIdx.x * 256 + threadIdx.x;
  if (i < n) out[i] = f2bf(v);
}

// ---------------- trig tables ----------------
__global__ void k_tables(float* __restrict__ T, float* __restrict__ Tt,
                         float2* __restrict__ D, float2* __restrict__ Dt) {
  int idx = blockIdx.x * blockDim.x + threadIdx.x;
  if (idx < CROP * N1S) {
    int a = idx / N1S, p = idx % N1S;
    int v = (p + 1) * (a - 128);
    int t = v % 512; if (t < 0) t += 512; if (t >= 256) t -= 512;
    float s = sinf((float)t * (PI2 / 512.0f));
    T[a * N1S + p] = s;
    Tt[p * CROP + a] = s;
  }
  if (idx < NOUT * CROP) {
    int k = idx / CROP, j = idx % CROP;
    int v = k * (j - 127);
    int t = v % 513; if (t < 0) t += 513; if (t > 256) t -= 513;
    float ang = (float)t * (PI2 / 513.0f);
    float2 d = make_float2(cosf(ang), -sinf(ang));
    D[k * CROP + j] = d;
    Dt[j * NOUT + k] = d;
  }
}

// ---------------- weight prep (validated r16): pack per-layer weights in consumption order ----------------
__global__ void k_wprep(const float* __restrict__ w1re, const float* __restrict__ w1im,
                        const float* __restrict__ w2re, const float* __restrict__ w2im,
                        const float* __restrict__ w3re, const float* __restrict__ w3im,
                        float* __restrict__ wp) {
  int p = blockIdx.x * 256 + threadIdx.x;
  if (p >= 19584) return;
  int l, off;
  if      (p < 576)   { l = 0; off = 0; }
  else if (p < 5184)  { l = 1; off = 576; }
  else if (p < 9792)  { l = 2; off = 5184; }
  else if (p < 14400) { l = 3; off = 9792; }
  else if (p < 19008) { l = 4; off = 14400; }
  else                { l = 5; off = 19008; }
  int q = p - off;
  int cin  = (l == 0) ? 1 : 8;
  int cout = (l == 5) ? 1 : 8;
  int per_b = cin * cout * 9;
  int b = q / per_b, rem = q % per_b;
  int c = rem / (cout * 9), rem2 = rem % (cout * 9);
  int o = rem2 / 9, t9 = rem2 % 9;
  int di = t9 / 3, dj = t9 % 3;
  const float *wre, *wim;
  if (l == 0 || l == 5) { wre = w1re; wim = w1im; }
  else if (l == 1 || l == 4) { wre = w2re; wim = w2im; }
  else { wre = w3re; wim = w3im; }
  bool trans = (l >= 3);
  float wr, wi;
  if (trans) {
    int widx = (((b * cin + c) * cout + o) * 3 + dj) * 3 + di;
    wr = wre[widx]; wi = -wim[widx];
  } else {
    int widx = (((b * cout + o) * cin + c) * 3 + di) * 3 + dj;
    wr = wre[widx]; wi = wim[widx];
  }
  wp[2 * p] = wr;
  wp[2 * p + 1] = wi;
}

// ======== LDS-tiled GEMM kernels: 32x64 tile, 512 thr, 4 out/thr (validated r13) ========

__global__ __launch_bounds__(512) void k_dst1(const float* __restrict__ r,
                                              const float* __restrict__ T,
                                              float* __restrict__ tmp) {
  __shared__ float As[32][16];
  __shared__ float Bs[16][64];
  const int tx = threadIdx.x, ty = threadIdx.y;
  const int tid = ty * 64 + tx;
  const int b = blockIdx.z;
  const int n = blockIdx.x * 64 + tx;
  const int a_base = blockIdx.y * 32;
  const float* rb = r + (size_t)b * N1S * N1S;
  float acc[4] = {};
  for (int mc = 0; mc < N1S; mc += 16) {
    { int row = tid / 16, col = tid % 16;
      int a = a_base + row, m = mc + col;
      As[row][col] = (a < CROP && m < N1S) ? T[a * N1S + m] : 0.f; }
    { int row = tid / 64, col = tid % 64;
      #pragma unroll
      for (int rr = 0; rr < 2; ++rr) {
        int m = mc + row + rr * 8, nn = blockIdx.x * 64 + col;
        Bs[row + rr * 8][col] = (m < N1S && nn < N1S) ? rb[m * N1S + nn] : 0.f;
      } }
    __syncthreads();
    #pragma unroll
    for (int jj = 0; jj < 16; ++jj) {
      float x = Bs[jj][tx];
      #pragma unroll
      for (int q = 0; q < 4; ++q)
        acc[q] = fmaf(As[ty * 4 + q][jj], x, acc[q]);
    }
    __syncthreads();
  }
  if (n < N1S) {
    #pragma unroll
    for (int q = 0; q < 4; ++q) {
      int a = a_base + ty * 4 + q;
      if (a < CROP) tmp[((size_t)b * CROP + a) * N1S + n] = acc[q];
    }
  }
}

__global__ __launch_bounds__(512) void k_dst2(const float* __restrict__ tmp,
                                              const float* __restrict__ Tt,
                                              float2* __restrict__ z0) {
  __shared__ float As[32][16];
  __shared__ float Bs[16][64];
  const int tx = threadIdx.x, ty = threadIdx.y;
  const int tid = ty * 64 + tx;
  const int b = blockIdx.z;
  const int a2 = blockIdx.x * 64 + tx;
  const int a_base = blockIdx.y * 32;
  const float* tb = tmp + (size_t)b * CROP * N1S;
  float acc[4] = {};
  for (int nc = 0; nc < N1S; nc += 16) {
    { int row = tid / 16, col = tid % 16;
      int a1 = a_base + row, nn = nc + col;
      As[row][col] = (a1 < CROP && nn < N1S) ? tb[a1 * N1S + nn] : 0.f; }
    { int row = tid / 64, col = tid % 64;
      #pragma unroll
      for (int rr = 0; rr < 2; ++rr) {
        int nn = nc + row + rr * 8, aa2 = blockIdx.x * 64 + col;
        Bs[row + rr * 8][col] = (nn < N1S && aa2 < CROP) ? Tt[nn * CROP + aa2] : 0.f;
      } }
    __syncthreads();
    #pragma unroll
    for (int jj = 0; jj < 16; ++jj) {
      float x = Bs[jj][tx];
      #pragma unroll
      for (int q = 0; q < 4; ++q)
        acc[q] = fmaf(As[ty * 4 + q][jj], x, acc[q]);
    }
    __syncthreads();
  }
  if (a2 < CROP) {
    #pragma unroll
    for (int q = 0; q < 4; ++q) {
      int a1 = a_base + ty * 4 + q;
      if (a1 < CROP)
        z0[((size_t)b * CROP + a1) * CROP + a2] = make_float2(acc[q] * (-1.0f / 65536.0f), 0.f);
    }
  }
}

__global__ __launch_bounds__(512) void k_f1(const float2* __restrict__ z,
                                            const float2* __restrict__ D,
                                            float2* __restrict__ t) {
  __shared__ float2 As[32][16];
  __shared__ float2 Bs[16][64];
  const int tx = threadIdx.x, ty = threadIdx.y;
  const int tid = ty * 64 + tx;
  const int b = blockIdx.z;
  const int j2 = blockIdx.x * 64 + tx;
  const int k_base = blockIdx.y * 32;
  const float2* zb = z + (size_t)b * CC;
  float tr[4] = {}, ti[4] = {};
  for (int jc = 0; jc < CROP; jc += 16) {
    { int row = tid / 16, col = tid % 16;
      int k = k_base + row, j1 = jc + col;
      As[row][col] = (k < NOUT && j1 < CROP) ? D[k * CROP + j1] : make_float2(0.f, 0.f); }
    { int row = tid / 64, col = tid % 64;
      #pragma unroll
      for (int rr = 0; rr < 2; ++rr) {
        int j1 = jc + row + rr * 8, jj2 = blockIdx.x * 64 + col;
        Bs[row + rr * 8][col] = (j1 < CROP && jj2 < CROP) ? zb[j1 * CROP + jj2] : make_float2(0.f, 0.f);
      } }
    __syncthreads();
    #pragma unroll
    for (int jj = 0; jj < 16; ++jj) {
      float2 zv = Bs[jj][tx];
      #pragma unroll
      for (int q = 0; q < 4; ++q) {
        float2 d = As[ty * 4 + q][jj];
        tr[q] = fmaf(d.x, zv.x, tr[q]); tr[q] = fmaf(-d.y, zv.y, tr[q]);
        ti[q] = fmaf(d.x, zv.y, ti[q]); ti[q] = fmaf(d.y, zv.x, ti[q]);
      }
    }
    __syncthreads();
  }
  if (j2 < CROP) {
    #pragma unroll
    for (int q = 0; q < 4; ++q) {
      int k = k_base + ty * 4 + q;
      if (k < NOUT)
        t[((size_t)b * NOUT + k) * CROP + j2] = make_float2(tr[q], ti[q]);
    }
  }
}

__global__ __launch_bounds__(512) void k_f2(const float2* __restrict__ t,
                                            const float2* __restrict__ Dt,
                                            ushort2* __restrict__ out) {
  __shared__ float2 As[32][16];
  __shared__ float2 Bs[16][64];
  const int tx = threadIdx.x, ty = threadIdx.y;
  const int tid = ty * 64 + tx;
  const int b = blockIdx.z;
  const int k2 = blockIdx.x * 64 + tx;
  const int k_base = blockIdx.y * 32;
  const float2* tb = t + (size_t)b * NOUT * CROP;
  float er[4] = {}, ei[4] = {};
  for (int jc = 0; jc < CROP; jc += 16) {
    { int row = tid / 16, col = tid % 16;
      int k1 = k_base + row, j = jc + col;
      As[row][col] = (k1 < NOUT && j < CROP) ? tb[k1 * CROP + j] : make_float2(0.f, 0.f); }
    { int row = tid / 64, col = tid % 64;
      #pragma unroll
      for (int rr = 0; rr < 2; ++rr) {
        int j = jc + row + rr * 8, kk2 = blockIdx.x * 64 + col;
        Bs[row + rr * 8][col] = (j < CROP && kk2 < NOUT) ? Dt[j * NOUT + kk2] : make_float2(0.f, 0.f);
      } }
    __syncthreads();
    #pragma unroll
    for (int jj = 0; jj < 16; ++jj) {
      float2 dv = Bs[jj][tx];
      #pragma unroll
      for (int q = 0; q < 4; ++q) {
        float2 tv = As[ty * 4 + q][jj];
        er[q] = fmaf(tv.x, dv.x, er[q]); er[q] = fmaf(-tv.y, dv.y, er[q]);
        ei[q] = fmaf(tv.x, dv.y, ei[q]); ei[q] = fmaf(tv.y, dv.x, ei[q]);
      }
    }
    __syncthreads();
  }
  if (k2 < NOUT) {
    #pragma unroll
    for (int q = 0; q < 4; ++q) {
      int k1 = k_base + ty * 4 + q;
      if (k1 < NOUT)
        out[((size_t)b * NOUT + k1) * NOUT + k2] = make_ushort2(f2bf(ei[q]), f2bf(er[q]));
    }
  }
}

// ---------------- FUSED 2-layer conv with LDS ALIASING (r21, best measured) ----------------
// Shared buffer reused: stage 18x18 halo -> layer1 (results in regs) -> barrier ->
// overwrite same LDS with 16x17 mid -> layer2 on 14x14 out. LDS = max(tile, mid).
template<int CIN, int COUT2, bool THETA_MID, bool REALIN>
__global__ __launch_bounds__(256) void k_fused(const float2* __restrict__ in,
                                               const float* __restrict__ wlA,
                                               const float* __restrict__ wlB,
                                               const float* __restrict__ tre,
                                               const float* __restrict__ tim,
                                               float2* __restrict__ out) {
  constexpr int TSZ = CIN * 18 * 18;
  constexpr int MSZ = 8 * 16 * 17;
  constexpr int SSZ = (TSZ > MSZ) ? TSZ : MSZ;
  __shared__ float2 sh[SSZ];
  const int b = blockIdx.z;
  const int tx = threadIdx.x, ty = threadIdx.y;
  const int tid = ty * 16 + tx;
  const int ox0 = blockIdx.x * 14, oy0 = blockIdx.y * 14;

  // stage input halo: sh[(c*18+iy)*18+ix] <-> global (oy0-2+iy, ox0-2+ix)
  const float2* inb = in + (size_t)b * CIN * CC;
  #pragma unroll 1
  for (int idx = tid; idx < TSZ; idx += 256) {
    int c = idx / (18 * 18), rem = idx % (18 * 18);
    int iy = rem / 18, ix = rem % 18;
    int gy = oy0 + iy - 2, gx = ox0 + ix - 2;
    float2 v = make_float2(0.f, 0.f);
    if (gy >= 0 && gy < CROP && gx >= 0 && gx < CROP)
      v = inb[(c * CROP + gy) * CROP + gx];
    sh[idx] = v;
  }
  __syncthreads();

  // layer1: 1 px/thread on the 16x16 mid tile -> registers
  float mr[8], mi[8];
  {
    const int gmy = oy0 - 1 + ty, gmx = ox0 - 1 + tx;
    const bool inside = (gmy >= 0 && gmy < CROP && gmx >= 0 && gmx < CROP);
    float ar[8], ai[8];
    #pragma unroll
    for (int o = 0; o < 8; ++o) { ar[o] = 0.f; ai[o] = 0.f; }
    #pragma unroll 1
    for (int c = 0; c < CIN; ++c) {
      const float* wsc = wlA + (size_t)2 * ((b * CIN + c) * 8 * 9);
      float xr[9], xi[9];
      #pragma unroll
      for (int t9 = 0; t9 < 9; ++t9) {
        float2 v = sh[(c * 18 + ty + t9 / 3) * 18 + tx + t9 % 3];
        xr[t9] = v.x; if (!REALIN) xi[t9] = v.y;
      }
      #pragma unroll
      for (int o = 0; o < 8; ++o) {
        #pragma unroll
        for (int t9 = 0; t9 < 9; ++t9) {
          float wr = wsc[(o * 9 + t9) * 2];
          float wi = wsc[(o * 9 + t9) * 2 + 1];
          if (REALIN) {
            ar[o] = fmaf(wr, xr[t9], ar[o]);
            ai[o] = fmaf(wi, xr[t9], ai[o]);
          } else {
            ar[o] = fmaf(wr, xr[t9], ar[o]);
            ar[o] = fmaf(-wi, xi[t9], ar[o]);
            ai[o] = fmaf(wr, xi[t9], ai[o]);
            ai[o] = fmaf(wi, xr[t9], ai[o]);
          }
        }
      }
    }
    #pragma unroll
    for (int o = 0; o < 8; ++o) {
      float rv = ar[o], iv = ai[o];
      if (THETA_MID && inside) {
        size_t tix = ((size_t)(b * 8 + o) * CROP + gmy) * CROP + gmx;
        float trv = tre[tix], tiv = tim[tix];
        float nr = rv * trv - iv * tiv, ni = rv * tiv + iv * trv;
        rv = nr; iv = ni;
      }
      mr[o] = inside ? rv : 0.f;
      mi[o] = inside ? iv : 0.f;
    }
  }
  __syncthreads();   // all tile reads done -> safe to overwrite

  // write mid into the SAME LDS region: sh[(o*16+ty)*17+tx]
  #pragma unroll
  for (int o = 0; o < 8; ++o)
    sh[(o * 16 + ty) * 17 + tx] = make_float2(mr[o], mi[o]);
  __syncthreads();

  // layer2: 14x14 outputs; taps sh[(c*16+ty+di)*17+tx+dj]
  if (tx < 14 && ty < 14) {
    const int oy = oy0 + ty, ox = ox0 + tx;
    if (oy < CROP && ox < CROP) {
      float ar[COUT2], ai[COUT2];
      #pragma unroll
      for (int o = 0; o < COUT2; ++o) { ar[o] = 0.f; ai[o] = 0.f; }
      #pragma unroll 1
      for (int c = 0; c < 8; ++c) {
        const float* wsc = wlB + (size_t)2 * ((b * 8 + c) * COUT2 * 9);
        float xr[9], xi[9];
        #pragma unroll
        for (int t9 = 0; t9 < 9; ++t9) {
          float2 v = sh[(c * 16 + ty + t9 / 3) * 17 + tx + t9 % 3];
          xr[t9] = v.x; xi[t9] = v.y;
        }
        #pragma unroll
        for (int o = 0; o < COUT2; ++o) {
          #pragma unroll
          for (int t9 = 0; t9 < 9; ++t9) {
            float wr = wsc[(o * 9 + t9) * 2];
            float wi = wsc[(o * 9 + t9) * 2 + 1];
            ar[o] = fmaf(wr, xr[t9], ar[o]);
            ar[o] = fmaf(-wi, xi[t9], ar[o]);
            ai[o] = fmaf(wr, xi[t9], ai[o]);
            ai[o] = fmaf(wi, xr[t9], ai[o]);
          }
        }
      }
      float2* outb = out + (size_t)b * COUT2 * CC;
      #pragma unroll
      for (int o = 0; o < COUT2; ++o)
        outb[(o * CROP + oy) * CROP + ox] = make_float2(ar[o], ai[o]);
    }
  }
}

extern "C" void kernel_launch(void* const* d_in, const int* in_sizes, int n_in,
                              void* d_out, int out_size, void* d_ws, size_t ws_size,
                              hipStream_t stream) {
  (void)ws_size;
  static const int EXP[9] = {520200, 576, 576, 4608, 4608, 4608, 4608, 4227136, 4227136};
  int bad = -1;
  if (n_in != 9) bad = 90;
  else for (int i = 0; i < 9; ++i) if (in_sizes[i] != EXP[i]) { bad = i; break; }
  if (bad >= 0) {
    float v = (bad == 90) ? 99.0f : (100.0f + (float)bad);
    k_fill<<<(out_size + 255) / 256, 256, 0, stream>>>((unsigned short*)d_out, out_size, v);
    return;
  }

  const float* r    = (const float*)d_in[0];
  const float* w1re = (const float*)d_in[1];
  const float* w1im = (const float*)d_in[2];
  const float* w2re = (const float*)d_in[3];
  const float* w2im = (const float*)d_in[4];
  const float* w3re = (const float*)d_in[5];
  const float* w3im = (const float*)d_in[6];
  const float* thre = (const float*)d_in[7];
  const float* thim = (const float*)d_in[8];

  float* ws = (float*)d_ws;
  size_t off = 0;
  auto alloc = [&](size_t n) { float* p = ws + off; off += (n + 63) & ~(size_t)63; return p; };
  float*  T    = alloc((size_t)CROP * N1S);
  float*  Tt   = alloc((size_t)N1S * CROP);
  float2* D    = (float2*)alloc((size_t)NOUT * CROP * 2);
  float2* Dt   = (float2*)alloc((size_t)CROP * NOUT * 2);
  float*  wp   = alloc((size_t)2 * 19584);
  float*  tmpA = alloc((size_t)NB * CROP * N1S);
  float2* z0   = (float2*)alloc((size_t)NB * CC * 2);
  float2* tmpF = (float2*)alloc((size_t)NB * NOUT * CROP * 2);
  float2* A    = (float2*)alloc((size_t)NB * CH * CC * 2);
  float2* Bb   = (float2*)alloc((size_t)NB * CH * CC * 2);

  k_tables<<<dim3((CROP * N1S + 255) / 256), dim3(256), 0, stream>>>(T, Tt, D, Dt);
  k_wprep<<<dim3(77), dim3(256), 0, stream>>>(w1re, w1im, w2re, w2im, w3re, w3im, wp);
  k_dst1<<<dim3(4, 9, NB), dim3(64, 8), 0, stream>>>(r, T, tmpA);
  k_dst2<<<dim3(5, 9, NB), dim3(64, 8), 0, stream>>>(tmpA, Tt, z0);

  dim3 fgrid(19, 19, NB), fblk(16, 16);
  // {conv1+conv2}, {conv3*theta+convT3}, {convT2+convT1}
  k_fused<1, 8, false, true ><<<fgrid, fblk, 0, stream>>>(z0, wp + 2 * 0,     wp + 2 * 576,   nullptr, nullptr, A);
  k_fused<8, 8, true , false><<<fgrid, fblk, 0, stream>>>(A,  wp + 2 * 5184,  wp + 2 * 9792,  thre, thim, Bb);
  k_fused<8, 1, false, false><<<fgrid, fblk, 0, stream>>>(Bb, wp + 2 * 14400, wp + 2 * 19008, nullptr, nullptr, z0);

  k_f1<<<dim3(5, 8, NB), dim3(64, 8), 0, stream>>>(z0, D, tmpF);
  k_f2<<<dim3(4, 8, NB), dim3(64, 8), 0, stream>>>(tmpF, Dt, (ushort2*)d_out);
}

// Round 26
// 299.428 us; speedup vs baseline: 1.3015x; 1.0124x over previous
//
#include <hip/hip_runtime.h>

#define NB 8
#define CH 8
#define N1S 255
#define CROP 257
#define NOUT 255
#define CC (CROP * CROP)   // 66049

static constexpr float PI2 = 6.28318530717958647692f;

__device__ inline unsigned short f2bf(float f) {
  unsigned int u = __float_as_uint(f);
  unsigned int lsb = (u >> 16) & 1u;
  u += 0x7fffu + lsb;
  return (unsigned short)(u >> 16);
}

__global__ void k_fill(unsigned short* __restrict__ out, int n, float v) {
  int i = blockIdx.x * 256 + threadIdx.x;
  if (i < n) out[i] = f2bf(v);
}

// ---------------- trig tables ----------------
__global__ void k_tables(float* __restrict__ T, float* __restrict__ Tt,
                         float2* __restrict__ D, float2* __restrict__ Dt) {
  int idx = blockIdx.x * blockDim.x + threadIdx.x;
  if (idx < CROP * N1S) {
    int a = idx / N1S, p = idx % N1S;
    int v = (p + 1) * (a - 128);
    int t = v % 512; if (t < 0) t += 512; if (t >= 256) t -= 512;
    float s = sinf((float)t * (PI2 / 512.0f));
    T[a * N1S + p] = s;
    Tt[p * CROP + a] = s;
  }
  if (idx < NOUT * CROP) {
    int k = idx / CROP, j = idx % CROP;
    int v = k * (j - 127);
    int t = v % 513; if (t < 0) t += 513; if (t > 256) t -= 513;
    float ang = (float)t * (PI2 / 513.0f);
    float2 d = make_float2(cosf(ang), -sinf(ang));
    D[k * CROP + j] = d;
    Dt[j * NOUT + k] = d;
  }
}

// ---------------- weight prep (validated r16): pack per-layer weights in consumption order ----------------
__global__ void k_wprep(const float* __restrict__ w1re, const float* __restrict__ w1im,
                        const float* __restrict__ w2re, const float* __restrict__ w2im,
                        const float* __restrict__ w3re, const float* __restrict__ w3im,
                        float* __restrict__ wp) {
  int p = blockIdx.x * 256 + threadIdx.x;
  if (p >= 19584) return;
  int l, off;
  if      (p < 576)   { l = 0; off = 0; }
  else if (p < 5184)  { l = 1; off = 576; }
  else if (p < 9792)  { l = 2; off = 5184; }
  else if (p < 14400) { l = 3; off = 9792; }
  else if (p < 19008) { l = 4; off = 14400; }
  else                { l = 5; off = 19008; }
  int q = p - off;
  int cin  = (l == 0) ? 1 : 8;
  int cout = (l == 5) ? 1 : 8;
  int per_b = cin * cout * 9;
  int b = q / per_b, rem = q % per_b;
  int c = rem / (cout * 9), rem2 = rem % (cout * 9);
  int o = rem2 / 9, t9 = rem2 % 9;
  int di = t9 / 3, dj = t9 % 3;
  const float *wre, *wim;
  if (l == 0 || l == 5) { wre = w1re; wim = w1im; }
  else if (l == 1 || l == 4) { wre = w2re; wim = w2im; }
  else { wre = w3re; wim = w3im; }
  bool trans = (l >= 3);
  float wr, wi;
  if (trans) {
    int widx = (((b * cin + c) * cout + o) * 3 + dj) * 3 + di;
    wr = wre[widx]; wi = -wim[widx];
  } else {
    int widx = (((b * cout + o) * cin + c) * 3 + di) * 3 + dj;
    wr = wre[widx]; wi = wim[widx];
  }
  wp[2 * p] = wr;
  wp[2 * p + 1] = wi;
}

// ======== LDS-tiled GEMM kernels: 32x64 tile, 512 thr, 4 out/thr (validated r13) ========

__global__ __launch_bounds__(512) void k_dst1(const float* __restrict__ r,
                                              const float* __restrict__ T,
                                              float* __restrict__ tmp) {
  __shared__ float As[32][16];
  __shared__ float Bs[16][64];
  const int tx = threadIdx.x, ty = threadIdx.y;
  const int tid = ty * 64 + tx;
  const int b = blockIdx.z;
  const int n = blockIdx.x * 64 + tx;
  const int a_base = blockIdx.y * 32;
  const float* rb = r + (size_t)b * N1S * N1S;
  float acc[4] = {};
  for (int mc = 0; mc < N1S; mc += 16) {
    { int row = tid / 16, col = tid % 16;
      int a = a_base + row, m = mc + col;
      As[row][col] = (a < CROP && m < N1S) ? T[a * N1S + m] : 0.f; }
    { int row = tid / 64, col = tid % 64;
      #pragma unroll
      for (int rr = 0; rr < 2; ++rr) {
        int m = mc + row + rr * 8, nn = blockIdx.x * 64 + col;
        Bs[row + rr * 8][col] = (m < N1S && nn < N1S) ? rb[m * N1S + nn] : 0.f;
      } }
    __syncthreads();
    #pragma unroll
    for (int jj = 0; jj < 16; ++jj) {
      float x = Bs[jj][tx];
      #pragma unroll
      for (int q = 0; q < 4; ++q)
        acc[q] = fmaf(As[ty * 4 + q][jj], x, acc[q]);
    }
    __syncthreads();
  }
  if (n < N1S) {
    #pragma unroll
    for (int q = 0; q < 4; ++q) {
      int a = a_base + ty * 4 + q;
      if (a < CROP) tmp[((size_t)b * CROP + a) * N1S + n] = acc[q];
    }
  }
}

__global__ __launch_bounds__(512) void k_dst2(const float* __restrict__ tmp,
                                              const float* __restrict__ Tt,
                                              float2* __restrict__ z0) {
  __shared__ float As[32][16];
  __shared__ float Bs[16][64];
  const int tx = threadIdx.x, ty = threadIdx.y;
  const int tid = ty * 64 + tx;
  const int b = blockIdx.z;
  const int a2 = blockIdx.x * 64 + tx;
  const int a_base = blockIdx.y * 32;
  const float* tb = tmp + (size_t)b * CROP * N1S;
  float acc[4] = {};
  for (int nc = 0; nc < N1S; nc += 16) {
    { int row = tid / 16, col = tid % 16;
      int a1 = a_base + row, nn = nc + col;
      As[row][col] = (a1 < CROP && nn < N1S) ? tb[a1 * N1S + nn] : 0.f; }
    { int row = tid / 64, col = tid % 64;
      #pragma unroll
      for (int rr = 0; rr < 2; ++rr) {
        int nn = nc + row + rr * 8, aa2 = blockIdx.x * 64 + col;
        Bs[row + rr * 8][col] = (nn < N1S && aa2 < CROP) ? Tt[nn * CROP + aa2] : 0.f;
      } }
    __syncthreads();
    #pragma unroll
    for (int jj = 0; jj < 16; ++jj) {
      float x = Bs[jj][tx];
      #pragma unroll
      for (int q = 0; q < 4; ++q)
        acc[q] = fmaf(As[ty * 4 + q][jj], x, acc[q]);
    }
    __syncthreads();
  }
  if (a2 < CROP) {
    #pragma unroll
    for (int q = 0; q < 4; ++q) {
      int a1 = a_base + ty * 4 + q;
      if (a1 < CROP)
        z0[((size_t)b * CROP + a1) * CROP + a2] = make_float2(acc[q] * (-1.0f / 65536.0f), 0.f);
    }
  }
}

__global__ __launch_bounds__(512) void k_f1(const float2* __restrict__ z,
                                            const float2* __restrict__ D,
                                            float2* __restrict__ t) {
  __shared__ float2 As[32][16];
  __shared__ float2 Bs[16][64];
  const int tx = threadIdx.x, ty = threadIdx.y;
  const int tid = ty * 64 + tx;
  const int b = blockIdx.z;
  const int j2 = blockIdx.x * 64 + tx;
  const int k_base = blockIdx.y * 32;
  const float2* zb = z + (size_t)b * CC;
  float tr[4] = {}, ti[4] = {};
  for (int jc = 0; jc < CROP; jc += 16) {
    { int row = tid / 16, col = tid % 16;
      int k = k_base + row, j1 = jc + col;
      As[row][col] = (k < NOUT && j1 < CROP) ? D[k * CROP + j1] : make_float2(0.f, 0.f); }
    { int row = tid / 64, col = tid % 64;
      #pragma unroll
      for (int rr = 0; rr < 2; ++rr) {
        int j1 = jc + row + rr * 8, jj2 = blockIdx.x * 64 + col;
        Bs[row + rr * 8][col] = (j1 < CROP && jj2 < CROP) ? zb[j1 * CROP + jj2] : make_float2(0.f, 0.f);
      } }
    __syncthreads();
    #pragma unroll
    for (int jj = 0; jj < 16; ++jj) {
      float2 zv = Bs[jj][tx];
      #pragma unroll
      for (int q = 0; q < 4; ++q) {
        float2 d = As[ty * 4 + q][jj];
        tr[q] = fmaf(d.x, zv.x, tr[q]); tr[q] = fmaf(-d.y, zv.y, tr[q]);
        ti[q] = fmaf(d.x, zv.y, ti[q]); ti[q] = fmaf(d.y, zv.x, ti[q]);
      }
    }
    __syncthreads();
  }
  if (j2 < CROP) {
    #pragma unroll
    for (int q = 0; q < 4; ++q) {
      int k = k_base + ty * 4 + q;
      if (k < NOUT)
        t[((size_t)b * NOUT + k) * CROP + j2] = make_float2(tr[q], ti[q]);
    }
  }
}

__global__ __launch_bounds__(512) void k_f2(const float2* __restrict__ t,
                                            const float2* __restrict__ Dt,
                                            ushort2* __restrict__ out) {
  __shared__ float2 As[32][16];
  __shared__ float2 Bs[16][64];
  const int tx = threadIdx.x, ty = threadIdx.y;
  const int tid = ty * 64 + tx;
  const int b = blockIdx.z;
  const int k2 = blockIdx.x * 64 + tx;
  const int k_base = blockIdx.y * 32;
  const float2* tb = t + (size_t)b * NOUT * CROP;
  float er[4] = {}, ei[4] = {};
  for (int jc = 0; jc < CROP; jc += 16) {
    { int row = tid / 16, col = tid % 16;
      int k1 = k_base + row, j = jc + col;
      As[row][col] = (k1 < NOUT && j < CROP) ? tb[k1 * CROP + j] : make_float2(0.f, 0.f); }
    { int row = tid / 64, col = tid % 64;
      #pragma unroll
      for (int rr = 0; rr < 2; ++rr) {
        int j = jc + row + rr * 8, kk2 = blockIdx.x * 64 + col;
        Bs[row + rr * 8][col] = (j < CROP && kk2 < NOUT) ? Dt[j * NOUT + kk2] : make_float2(0.f, 0.f);
      } }
    __syncthreads();
    #pragma unroll
    for (int jj = 0; jj < 16; ++jj) {
      float2 dv = Bs[jj][tx];
      #pragma unroll
      for (int q = 0; q < 4; ++q) {
        float2 tv = As[ty * 4 + q][jj];
        er[q] = fmaf(tv.x, dv.x, er[q]); er[q] = fmaf(-tv.y, dv.y, er[q]);
        ei[q] = fmaf(tv.x, dv.y, ei[q]); ei[q] = fmaf(tv.y, dv.x, ei[q]);
      }
    }
    __syncthreads();
  }
  if (k2 < NOUT) {
    #pragma unroll
    for (int q = 0; q < 4; ++q) {
      int k1 = k_base + ty * 4 + q;
      if (k1 < NOUT)
        out[((size_t)b * NOUT + k1) * NOUT + k2] = make_ushort2(f2bf(ei[q]), f2bf(er[q]));
    }
  }
}

// ---------------- FUSED 2-layer conv body (r21, best measured) as inlined device fn ----------------
template<int CIN, int COUT2, bool THETA_MID, bool REALIN>
__device__ __forceinline__ void fused_body(const float2* __restrict__ in,
                                           const float* __restrict__ wlA,
                                           const float* __restrict__ wlB,
                                           const float* __restrict__ tre,
                                           const float* __restrict__ tim,
                                           float2* __restrict__ out) {
  constexpr int TSZ = CIN * 18 * 18;
  constexpr int MSZ = 8 * 16 * 17;
  constexpr int SSZ = (TSZ > MSZ) ? TSZ : MSZ;
  __shared__ float2 sh[SSZ];
  const int b = blockIdx.z;
  const int tx = threadIdx.x, ty = threadIdx.y;
  const int tid = ty * 16 + tx;
  const int ox0 = blockIdx.x * 14, oy0 = blockIdx.y * 14;

  const float2* inb = in + (size_t)b * CIN * CC;
  #pragma unroll 1
  for (int idx = tid; idx < TSZ; idx += 256) {
    int c = idx / (18 * 18), rem = idx % (18 * 18);
    int iy = rem / 18, ix = rem % 18;
    int gy = oy0 + iy - 2, gx = ox0 + ix - 2;
    float2 v = make_float2(0.f, 0.f);
    if (gy >= 0 && gy < CROP && gx >= 0 && gx < CROP)
      v = inb[(c * CROP + gy) * CROP + gx];
    sh[idx] = v;
  }
  __syncthreads();

  float mr[8], mi[8];
  {
    const int gmy = oy0 - 1 + ty, gmx = ox0 - 1 + tx;
    const bool inside = (gmy >= 0 && gmy < CROP && gmx >= 0 && gmx < CROP);
    float ar[8], ai[8];
    #pragma unroll
    for (int o = 0; o < 8; ++o) { ar[o] = 0.f; ai[o] = 0.f; }
    #pragma unroll 1
    for (int c = 0; c < CIN; ++c) {
      const float* wsc = wlA + (size_t)2 * ((b * CIN + c) * 8 * 9);
      float xr[9], xi[9];
      #pragma unroll
      for (int t9 = 0; t9 < 9; ++t9) {
        float2 v = sh[(c * 18 + ty + t9 / 3) * 18 + tx + t9 % 3];
        xr[t9] = v.x; if (!REALIN) xi[t9] = v.y;
      }
      #pragma unroll
      for (int o = 0; o < 8; ++o) {
        #pragma unroll
        for (int t9 = 0; t9 < 9; ++t9) {
          float wr = wsc[(o * 9 + t9) * 2];
          float wi = wsc[(o * 9 + t9) * 2 + 1];
          if (REALIN) {
            ar[o] = fmaf(wr, xr[t9], ar[o]);
            ai[o] = fmaf(wi, xr[t9], ai[o]);
          } else {
            ar[o] = fmaf(wr, xr[t9], ar[o]);
            ar[o] = fmaf(-wi, xi[t9], ar[o]);
            ai[o] = fmaf(wr, xi[t9], ai[o]);
            ai[o] = fmaf(wi, xr[t9], ai[o]);
          }
        }
      }
    }
    #pragma unroll
    for (int o = 0; o < 8; ++o) {
      float rv = ar[o], iv = ai[o];
      if (THETA_MID && inside) {
        size_t tix = ((size_t)(b * 8 + o) * CROP + gmy) * CROP + gmx;
        float trv = tre[tix], tiv = tim[tix];
        float nr = rv * trv - iv * tiv, ni = rv * tiv + iv * trv;
        rv = nr; iv = ni;
      }
      mr[o] = inside ? rv : 0.f;
      mi[o] = inside ? iv : 0.f;
    }
  }
  __syncthreads();

  #pragma unroll
  for (int o = 0; o < 8; ++o)
    sh[(o * 16 + ty) * 17 + tx] = make_float2(mr[o], mi[o]);
  __syncthreads();

  if (tx < 14 && ty < 14) {
    const int oy = oy0 + ty, ox = ox0 + tx;
    if (oy < CROP && ox < CROP) {
      float ar[COUT2], ai[COUT2];
      #pragma unroll
      for (int o = 0; o < COUT2; ++o) { ar[o] = 0.f; ai[o] = 0.f; }
      #pragma unroll 1
      for (int c = 0; c < 8; ++c) {
        const float* wsc = wlB + (size_t)2 * ((b * 8 + c) * COUT2 * 9);
        float xr[9], xi[9];
        #pragma unroll
        for (int t9 = 0; t9 < 9; ++t9) {
          float2 v = sh[(c * 16 + ty + t9 / 3) * 17 + tx + t9 % 3];
          xr[t9] = v.x; xi[t9] = v.y;
        }
        #pragma unroll
        for (int o = 0; o < COUT2; ++o) {
          #pragma unroll
          for (int t9 = 0; t9 < 9; ++t9) {
            float wr = wsc[(o * 9 + t9) * 2];
            float wi = wsc[(o * 9 + t9) * 2 + 1];
            ar[o] = fmaf(wr, xr[t9], ar[o]);
            ar[o] = fmaf(-wi, xi[t9], ar[o]);
            ai[o] = fmaf(wr, xi[t9], ai[o]);
            ai[o] = fmaf(wi, xr[t9], ai[o]);
          }
        }
      }
      float2* outb = out + (size_t)b * COUT2 * CC;
      #pragma unroll
      for (int o = 0; o < COUT2; ++o)
        outb[(o * CROP + oy) * CROP + ox] = make_float2(ar[o], ai[o]);
    }
  }
}

// Distinctly-NAMED wrappers so rocprof attributes counters per stage.
__global__ __launch_bounds__(256) void k_fusedA(const float2* __restrict__ in,
                                                const float* __restrict__ wlA,
                                                const float* __restrict__ wlB,
                                                float2* __restrict__ out) {
  fused_body<1, 8, false, true>(in, wlA, wlB, nullptr, nullptr, out);
}
__global__ __launch_bounds__(256) void k_fusedB(const float2* __restrict__ in,
                                                const float* __restrict__ wlA,
                                                const float* __restrict__ wlB,
                                                const float* __restrict__ tre,
                                                const float* __restrict__ tim,
                                                float2* __restrict__ out) {
  fused_body<8, 8, true, false>(in, wlA, wlB, tre, tim, out);
}
__global__ __launch_bounds__(256) void k_fusedC(const float2* __restrict__ in,
                                                const float* __restrict__ wlA,
                                                const float* __restrict__ wlB,
                                                float2* __restrict__ out) {
  fused_body<8, 1, false, false>(in, wlA, wlB, nullptr, nullptr, out);
}

extern "C" void kernel_launch(void* const* d_in, const int* in_sizes, int n_in,
                              void* d_out, int out_size, void* d_ws, size_t ws_size,
                              hipStream_t stream) {
  (void)ws_size;
  static const int EXP[9] = {520200, 576, 576, 4608, 4608, 4608, 4608, 4227136, 4227136};
  int bad = -1;
  if (n_in != 9) bad = 90;
  else for (int i = 0; i < 9; ++i) if (in_sizes[i] != EXP[i]) { bad = i; break; }
  if (bad >= 0) {
    float v = (bad == 90) ? 99.0f : (100.0f + (float)bad);
    k_fill<<<(out_size + 255) / 256, 256, 0, stream>>>((unsigned short*)d_out, out_size, v);
    return;
  }

  const float* r    = (const float*)d_in[0];
  const float* w1re = (const float*)d_in[1];
  const float* w1im = (const float*)d_in[2];
  const float* w2re = (const float*)d_in[3];
  const float* w2im = (const float*)d_in[4];
  const float* w3re = (const float*)d_in[5];
  const float* w3im = (const float*)d_in[6];
  const float* thre = (const float*)d_in[7];
  const float* thim = (const float*)d_in[8];

  float* ws = (float*)d_ws;
  size_t off = 0;
  auto alloc = [&](size_t n) { float* p = ws + off; off += (n + 63) & ~(size_t)63; return p; };
  float*  T    = alloc((size_t)CROP * N1S);
  float*  Tt   = alloc((size_t)N1S * CROP);
  float2* D    = (float2*)alloc((size_t)NOUT * CROP * 2);
  float2* Dt   = (float2*)alloc((size_t)CROP * NOUT * 2);
  float*  wp   = alloc((size_t)2 * 19584);
  float*  tmpA = alloc((size_t)NB * CROP * N1S);
  float2* z0   = (float2*)alloc((size_t)NB * CC * 2);
  float2* tmpF = (float2*)alloc((size_t)NB * NOUT * CROP * 2);
  float2* A    = (float2*)alloc((size_t)NB * CH * CC * 2);
  float2* Bb   = (float2*)alloc((size_t)NB * CH * CC * 2);

  k_tables<<<dim3((CROP * N1S + 255) / 256), dim3(256), 0, stream>>>(T, Tt, D, Dt);
  k_wprep<<<dim3(77), dim3(256), 0, stream>>>(w1re, w1im, w2re, w2im, w3re, w3im, wp);
  k_dst1<<<dim3(4, 9, NB), dim3(64, 8), 0, stream>>>(r, T, tmpA);
  k_dst2<<<dim3(5, 9, NB), dim3(64, 8), 0, stream>>>(tmpA, Tt, z0);

  dim3 fgrid(19, 19, NB), fblk(16, 16);
  // {conv1+conv2}, {conv3*theta+convT3}, {convT2+convT1}
  k_fusedA<<<fgrid, fblk, 0, stream>>>(z0, wp + 2 * 0,     wp + 2 * 576,   A);
  k_fusedB<<<fgrid, fblk, 0, stream>>>(A,  wp + 2 * 5184,  wp + 2 * 9792,  thre, thim, Bb);
  k_fusedC<<<fgrid, fblk, 0, stream>>>(Bb, wp + 2 * 14400, wp + 2 * 19008, z0);

  k_f1<<<dim3(5, 8, NB), dim3(64, 8), 0, stream>>>(z0, D, tmpF);
  k_f2<<<dim3(4, 8, NB), dim3(64, 8), 0, stream>>>(tmpF, Dt, (ushort2*)d_out);
}